// Round 2
// baseline (1438.987 us; speedup 1.0000x reference)
//
#include <hip/hip_runtime.h>
#include <hip/hip_bf16.h>

typedef unsigned short u16;
typedef short s16x8 __attribute__((ext_vector_type(8)));
typedef float f32x4 __attribute__((ext_vector_type(4)));

#define SCALE_F 0.17677669529663687f

// workspace layout (bytes). Peak ~202MB.
#define OFF_CM    ((size_t)0)                 // 64*12*2401*4 = 7,375,872
#define OFF_WQ    ((size_t)8<<20)             // qkvT  1152*384*2
#define OFF_WP    (OFF_WQ + 884736)           // projT 384*384*2
#define OFF_W1    (OFF_WP + 294912)           // fc1T  1536*384*2
#define OFF_W2    (OFF_W1 + 1179648)          // fc2T  384*1536*2
#define OFF_AWIN  ((size_t)12<<20)            // 77MB: A_win -> (reuse) ln2o
#define OFF_OBUF  ((size_t)90<<20)            // 77MB: attention output
#define OFF_ARENA ((size_t)168<<20)           // 35.8MB: qkv chunk / fc1 chunk

static __device__ __forceinline__ u16 f2b(float f) {
    unsigned u = __float_as_uint(f);
    u += 0x7fffu + ((u >> 16) & 1u);
    return (u16)(u >> 16);
}
static __device__ __forceinline__ float b2f(u16 u) {
    return __uint_as_float((unsigned)u << 16);
}

static __device__ __forceinline__ void mfma_bf16(f32x4& d, s16x8 a, s16x8 b) {
    asm("v_mfma_f32_16x16x32_bf16 %0, %1, %2, %0" : "+v"(d) : "v"(a), "v"(b));
}

static __device__ __forceinline__ void gload16(const void* g, void* l) {
    __builtin_amdgcn_global_load_lds(
        (const __attribute__((address_space(1))) unsigned int*)g,
        (__attribute__((address_space(3))) unsigned int*)l, 16, 0, 0);
}

// ---- combined mask+bias: CM[wpos][head][r*49+c] ----
__global__ void cm_kernel(const float* __restrict__ am, const float* __restrict__ pm,
                          const float* __restrict__ rpb, const int* __restrict__ ridx,
                          float* __restrict__ cmo)
{
    const int wpos = blockIdx.x, head = blockIdx.y;
    float* o = cmo + ((size_t)wpos*12 + head)*2401;
    const float* a = am + (size_t)wpos*2401;
    const float* p = pm + (size_t)wpos*2401;
    for (int e = threadIdx.x; e < 2401; e += 256)
        o[e] = a[e] + p[e] + rpb[ridx[e]*12 + head];
}

// ---- weight transpose+convert: Wt[n][k] = bf16(W[k][n]) ----
__global__ void wconv_kernel(const float* __restrict__ w, u16* __restrict__ wt,
                             int K, int N)
{
    const int k = blockIdx.x*256 + threadIdx.x;
    const int n = blockIdx.y;
    if (k < K) wt[(size_t)n*K + k] = f2b(w[(size_t)k*N + n]);
}

// ---- layernorm; WINDOWED=1 adds roll/pad/window-partition gather ----
template<int WINDOWED>
__global__ __launch_bounds__(256, 4)
void ln_kernel(const float* __restrict__ x, const float* __restrict__ g,
               const float* __restrict__ bt, u16* __restrict__ out)
{
    const int lane = threadIdx.x & 63;
    const int row = blockIdx.x*4 + (threadIdx.x >> 6);
    u16* orow = out + (size_t)row*384;
    const float* xr;
    if (WINDOWED) {
        const int win = row / 49, n = row - win*49;
        const int wpos = win & 63, b = win >> 6;
        const int n7 = n / 7;
        const int hp = (wpos >> 3)*7 + n7;
        if (hp < 4) {                 // zero-padded rows (wave-uniform)
            #pragma unroll
            for (int j=0;j<6;j++) orow[lane + 64*j] = 0;
            return;
        }
        const int wp = (wpos & 7)*7 + (n - n7*7);
        int h = hp - 1; if (h >= 52) h -= 52;   // (hp-4+3) % 52
        int w = wp + 3; if (w >= 56) w -= 56;
        xr = x + (((size_t)b*52 + h)*56 + w)*384;
    } else {
        xr = x + (size_t)row*384;
    }
    float v[6]; float sum = 0.f;
    #pragma unroll
    for (int j=0;j<6;j++){ v[j] = xr[lane + 64*j]; sum += v[j]; }
    #pragma unroll
    for (int m=1;m<64;m<<=1) sum += __shfl_xor(sum, m);
    const float mean = sum * (1.f/384.f);
    float var = 0.f;
    #pragma unroll
    for (int j=0;j<6;j++){ float d = v[j]-mean; var += d*d; }
    #pragma unroll
    for (int m=1;m<64;m<<=1) var += __shfl_xor(var, m);
    const float rstd = rsqrtf(var*(1.f/384.f) + 1e-5f);
    #pragma unroll
    for (int j=0;j<6;j++){
        const int c = lane + 64*j;
        orow[c] = f2b((v[j]-mean)*rstd*g[c] + bt[c]);
    }
}

// ---- generic bf16 GEMM: out[M][N] = A[M][K] @ Bt[N][K]^T + bias, epilogues:
// EPI 0: +bias -> bf16      EPI 2: gelu(+bias) -> bf16
// EPI 1: +bias +x(shortcut) with inverse-window scatter -> f32 x1
// EPI 3: +bias +x1 -> f32 (in-place on x1)
template<int EPI>
__global__ __launch_bounds__(256, 2)
void gemm_kernel(const u16* __restrict__ A, const u16* __restrict__ Bt,
                 const float* __restrict__ bias, void* __restrict__ outp,
                 const float* __restrict__ extra, int M, int N, int K)
{
    (void)M;
    __shared__ u16 Als[2][4096];
    __shared__ u16 Bls[2][4096];
    const int tid = threadIdx.x;
    const int lane = tid & 63;
    const int wid = tid >> 6;
    const int wr = wid >> 1, wc = wid & 1;
    const int r16 = lane & 15, kc = lane >> 4;
    const int m0 = blockIdx.y*128, n0 = blockIdx.x*128;
    const int srow = tid >> 2, schunk = tid & 3;
    const int nk = K >> 5;

    // source-chunk XOR swizzle keeps LDS dest linear (tid*16B) but spreads banks
    const u16* Ab = A  + (size_t)(m0 + srow)*K + (schunk ^ ((srow >> 1) & 3))*8;
    const u16* Bb = Bt + (size_t)(n0 + srow)*K + (schunk ^ ((srow >> 1) & 3))*8;
    const size_t rskip = (size_t)64*K;

    gload16(Ab,         &Als[0][tid*8]);
    gload16(Ab + rskip, &Als[0][2048 + tid*8]);
    gload16(Bb,         &Bls[0][tid*8]);
    gload16(Bb + rskip, &Bls[0][2048 + tid*8]);

    f32x4 acc[4][4] = {};
    const int swz = (kc ^ ((r16 >> 1) & 3))*8;
    for (int kt = 0; kt < nk; ++kt) {
        __syncthreads();
        if (kt + 1 < nk) {
            const int buf = (kt + 1) & 1;
            const u16* a = Ab + (kt+1)*32;
            const u16* b = Bb + (kt+1)*32;
            gload16(a,         &Als[buf][tid*8]);
            gload16(a + rskip, &Als[buf][2048 + tid*8]);
            gload16(b,         &Bls[buf][tid*8]);
            gload16(b + rskip, &Bls[buf][2048 + tid*8]);
        }
        const u16* as = Als[kt & 1];
        const u16* bs = Bls[kt & 1];
        s16x8 af[4], bfr[4];
        #pragma unroll
        for (int i=0;i<4;i++) {
            af[i]  = *(const s16x8*)&as[(64*wr + 16*i + r16)*32 + swz];
            bfr[i] = *(const s16x8*)&bs[(64*wc + 16*i + r16)*32 + swz];
        }
        #pragma unroll
        for (int i=0;i<4;i++)
            #pragma unroll
            for (int j=0;j<4;j++)
                mfma_bf16(acc[i][j], af[i], bfr[j]);
    }

    float bj[4];
    #pragma unroll
    for (int j=0;j<4;j++) bj[j] = bias[n0 + 64*wc + 16*j + r16];

    if constexpr (EPI == 0 || EPI == 2) {
        u16* out = (u16*)outp;
        #pragma unroll
        for (int i=0;i<4;i++)
          #pragma unroll
          for (int r=0;r<4;r++) {
            const size_t row = m0 + 64*wr + 16*i + 4*kc + r;
            #pragma unroll
            for (int j=0;j<4;j++) {
                const int col = n0 + 64*wc + 16*j + r16;
                float v = acc[i][j][r] + bj[j];
                if constexpr (EPI == 2) v = 0.5f*v*(1.f + erff(v*0.70710678118f));
                out[row*(size_t)N + col] = f2b(v);
            }
          }
    } else if constexpr (EPI == 3) {
        float* out = (float*)outp;
        #pragma unroll
        for (int i=0;i<4;i++)
          #pragma unroll
          for (int r=0;r<4;r++) {
            const size_t row = m0 + 64*wr + 16*i + 4*kc + r;
            #pragma unroll
            for (int j=0;j<4;j++) {
                const int col = n0 + 64*wc + 16*j + r16;
                out[row*(size_t)N + col] = extra[row*(size_t)N + col] + acc[i][j][r] + bj[j];
            }
          }
    } else { // EPI == 1
        float* out = (float*)outp;
        #pragma unroll
        for (int i=0;i<4;i++)
          #pragma unroll
          for (int r=0;r<4;r++) {
            const int row = m0 + 64*wr + 16*i + 4*kc + r;
            const int win = row / 49, n = row - win*49;
            const int wpos = win & 63, b = win >> 6;
            const int n7 = n / 7;
            const int hp = (wpos >> 3)*7 + n7;
            if (hp < 4) continue;               // dropped padded rows
            const int wp = (wpos & 7)*7 + (n - n7*7);
            int h = hp + 2; if (h >= 52) h -= 52;   // (hp-4+6) % 52
            int w = wp + 6; if (w >= 56) w -= 56;
            const size_t base = (((size_t)b*52 + h)*56 + w)*384;
            #pragma unroll
            for (int j=0;j<4;j++) {
                const int col = n0 + 64*wc + 16*j + r16;
                out[base + col] = extra[base + col] + acc[i][j][r] + bj[j];
            }
          }
    }
}

// ---- scalar-exact windowed attention: 1 wave per (window, head) ----
// Lane r (<49) owns output row r. K/V staged bf16 in LDS; all math fp32;
// exact 49-wide softmax (no padded columns, no fragment layouts).
__global__ __launch_bounds__(256, 2)
void attn_scalar(const u16* __restrict__ qkvc, const float* __restrict__ cm,
                 u16* __restrict__ o, int win_base)
{
    __shared__ u16 Kls[4][1568];
    __shared__ u16 Vls[4][1568];
    __shared__ float Sls[4][2401];
    const int tid = threadIdx.x, lane = tid & 63, wv = tid >> 6;
    const int u = blockIdx.x*4 + wv;
    const int wloc = u / 12, head = u - wloc*12;
    const int wglob = win_base + wloc;
    const int wpos = wglob & 63;
    const u16* base = qkvc + (size_t)wloc*49*1152 + head*32;

    for (int i = lane; i < 1568; i += 64) {
        const int row = i >> 5, d = i & 31;
        Kls[wv][i] = base[(size_t)row*1152 + 384 + d];
        Vls[wv][i] = base[(size_t)row*1152 + 768 + d];
    }
    __syncthreads();

    const int r = lane;
    if (r < 49) {
        float q[32];
        const u16* qp = base + (size_t)r*1152;
        #pragma unroll
        for (int d = 0; d < 32; ++d) q[d] = b2f(qp[d]) * SCALE_F;
        const float* cmb = cm + ((size_t)wpos*12 + head)*2401 + r*49;
        const u16* kw = Kls[wv];
        float* sw = Sls[wv] + r*49;
        float mx = -1e30f;
        for (int c = 0; c < 49; ++c) {
            float s = 0.f;
            #pragma unroll
            for (int d = 0; d < 32; ++d) s += q[d]*b2f(kw[c*32+d]);
            s += cmb[c];
            sw[c] = s;
            mx = fmaxf(mx, s);
        }
        float sm = 0.f;
        for (int c = 0; c < 49; ++c) { float e = __expf(sw[c]-mx); sm += e; sw[c] = e; }
        const float inv = 1.f/sm;
        float oa[32];
        #pragma unroll
        for (int d = 0; d < 32; ++d) oa[d] = 0.f;
        const u16* vw = Vls[wv];
        for (int c = 0; c < 49; ++c) {
            const float p = sw[c]*inv;
            #pragma unroll
            for (int d = 0; d < 32; ++d) oa[d] += p*b2f(vw[c*32+d]);
        }
        u16* op = o + (size_t)(wglob*49 + r)*384 + head*32;
        #pragma unroll
        for (int d = 0; d < 32; ++d) op[d] = f2b(oa[d]);
    }
}

extern "C" void kernel_launch(void* const* d_in, const int* in_sizes, int n_in,
                              void* d_out, int out_size, void* d_ws, size_t ws_size,
                              hipStream_t stream)
{
    (void)in_sizes; (void)n_in; (void)out_size; (void)ws_size;
    const float* x      = (const float*)d_in[0];
    const float* n1g    = (const float*)d_in[1];
    const float* n1b    = (const float*)d_in[2];
    const float* qkv_w  = (const float*)d_in[3];
    const float* qkv_b  = (const float*)d_in[4];
    const float* rpb    = (const float*)d_in[5];
    const float* proj_w = (const float*)d_in[6];
    const float* proj_b = (const float*)d_in[7];
    const float* n2g    = (const float*)d_in[8];
    const float* n2b    = (const float*)d_in[9];
    const float* fc1_w  = (const float*)d_in[10];
    const float* fc1_b  = (const float*)d_in[11];
    const float* fc2_w  = (const float*)d_in[12];
    const float* fc2_b  = (const float*)d_in[13];
    const float* amask  = (const float*)d_in[14];
    const float* pmask  = (const float*)d_in[15];
    const int*   ridx   = (const int*)d_in[16];

    char* ws = (char*)d_ws;
    float* cm    = (float*)(ws + OFF_CM);
    u16* wqkvT   = (u16*)(ws + OFF_WQ);
    u16* wprojT  = (u16*)(ws + OFF_WP);
    u16* wfc1T   = (u16*)(ws + OFF_W1);
    u16* wfc2T   = (u16*)(ws + OFF_W2);
    u16* awin    = (u16*)(ws + OFF_AWIN);
    u16* obuf    = (u16*)(ws + OFF_OBUF);
    u16* arena   = (u16*)(ws + OFF_ARENA);  // qkv chunk, later fc1 chunk
    u16* ln2o    = (u16*)(ws + OFF_AWIN);   // reuse (awin dead after QKV)
    float* x1    = (float*)d_out;           // x1 lives in d_out (in-place finish)

    cm_kernel  <<<dim3(64,12),  256, 0, stream>>>(amask, pmask, rpb, ridx, cm);
    wconv_kernel<<<dim3(2,1152),256, 0, stream>>>(qkv_w,  wqkvT, 384, 1152);
    wconv_kernel<<<dim3(2,384), 256, 0, stream>>>(proj_w, wprojT, 384, 384);
    wconv_kernel<<<dim3(2,1536),256, 0, stream>>>(fc1_w,  wfc1T, 384, 1536);
    wconv_kernel<<<dim3(6,384), 256, 0, stream>>>(fc2_w,  wfc2T, 1536, 384);

    ln_kernel<1><<<25088, 256, 0, stream>>>(x, n1g, n1b, awin);

    // QKV + attention in 8 chunks of 256 windows (12544 rows) each
    for (int c = 0; c < 8; ++c) {
        const u16* aA = awin + (size_t)c*12544*384;
        gemm_kernel<0><<<dim3(9,98), 256, 0, stream>>>(aA, wqkvT, qkv_b, arena, nullptr, 12544, 1152, 384);
        attn_scalar  <<<768, 256, 0, stream>>>(arena, cm, obuf, c*256);
    }

    gemm_kernel<1><<<dim3(3,784), 256, 0, stream>>>(obuf, wprojT, proj_b, x1, x, 100352, 384, 384);
    ln_kernel<0><<<23296, 256, 0, stream>>>(x1, n2g, n2b, ln2o);

    // MLP in 8 chunks of 11648 rows each
    for (int c = 0; c < 8; ++c) {
        const size_t ro = (size_t)c*11648;
        gemm_kernel<2><<<dim3(12,91), 256, 0, stream>>>(ln2o + ro*384, wfc1T, fc1_b, arena, nullptr, 11648, 1536, 384);
        gemm_kernel<3><<<dim3(3,91),  256, 0, stream>>>(arena, wfc2T, fc2_b, x1 + ro*384, x1 + ro*384, 11648, 384, 1536);
    }
}

// Round 6
// 1128.407 us; speedup vs baseline: 1.2752x; 1.2752x over previous
//
#include <hip/hip_runtime.h>
#include <hip/hip_bf16.h>

typedef unsigned short u16;
typedef short s16x8 __attribute__((ext_vector_type(8)));
typedef float f32x4 __attribute__((ext_vector_type(4)));

#define SCALE_F 0.17677669529663687f

// workspace layout (bytes). Fixed part ends at 168MB (R2-proven); arena adaptive.
#define OFF_CM    ((size_t)0)                 // 64*12*2401*4 = 7,375,872
#define OFF_WQ    ((size_t)8<<20)             // qkvT  1152*384*2
#define OFF_WP    (OFF_WQ + 884736)           // projT 384*384*2
#define OFF_W1    (OFF_WP + 294912)           // fc1T  1536*384*2
#define OFF_W2    (OFF_W1 + 1179648)          // fc2T  384*1536*2
#define OFF_AWIN  ((size_t)12<<20)            // 77MB: A_win -> (reuse) ln2o
#define OFF_OBUF  ((size_t)90<<20)            // 73.5MB: attention output
#define OFF_ARENA ((size_t)168<<20)           // qkv chunk / fc1 chunk (adaptive)

#define QKV_FULL  ((size_t)100352*1152*2)     // 231,211,008
#define FC1_FULL  ((size_t)93184*1536*2)      // 286,261,248

static __device__ __forceinline__ u16 f2b(float f) {
    unsigned u = __float_as_uint(f);
    u += 0x7fffu + ((u >> 16) & 1u);
    return (u16)(u >> 16);
}
static __device__ __forceinline__ float b2f(u16 u) {
    return __uint_as_float((unsigned)u << 16);
}

static __device__ __forceinline__ void mfma_bf16(f32x4& d, s16x8 a, s16x8 b) {
    asm("v_mfma_f32_16x16x32_bf16 %0, %1, %2, %0" : "+v"(d) : "v"(a), "v"(b));
}

static __device__ __forceinline__ void gload16(const void* g, void* l) {
    __builtin_amdgcn_global_load_lds(
        (const __attribute__((address_space(1))) unsigned int*)g,
        (__attribute__((address_space(3))) unsigned int*)l, 16, 0, 0);
}

// ---- combined mask+bias: CM[wpos][head][r*49+c] ----
__global__ void cm_kernel(const float* __restrict__ am, const float* __restrict__ pm,
                          const float* __restrict__ rpb, const int* __restrict__ ridx,
                          float* __restrict__ cmo)
{
    const int wpos = blockIdx.x, head = blockIdx.y;
    float* o = cmo + ((size_t)wpos*12 + head)*2401;
    const float* a = am + (size_t)wpos*2401;
    const float* p = pm + (size_t)wpos*2401;
    for (int e = threadIdx.x; e < 2401; e += 256)
        o[e] = a[e] + p[e] + rpb[ridx[e]*12 + head];
}

// ---- weight transpose+convert: Wt[n][k] = bf16(W[k][n]) ----
__global__ void wconv_kernel(const float* __restrict__ w, u16* __restrict__ wt,
                             int K, int N)
{
    const int k = blockIdx.x*256 + threadIdx.x;
    const int n = blockIdx.y;
    if (k < K) wt[(size_t)n*K + k] = f2b(w[(size_t)k*N + n]);
}

// ---- layernorm; WINDOWED=1 adds roll/pad/window-partition gather ----
template<int WINDOWED>
__global__ __launch_bounds__(256, 4)
void ln_kernel(const float* __restrict__ x, const float* __restrict__ g,
               const float* __restrict__ bt, u16* __restrict__ out)
{
    const int lane = threadIdx.x & 63;
    const int row = blockIdx.x*4 + (threadIdx.x >> 6);
    u16* orow = out + (size_t)row*384;
    const float* xr;
    if (WINDOWED) {
        const int win = row / 49, n = row - win*49;
        const int wpos = win & 63, b = win >> 6;
        const int n7 = n / 7;
        const int hp = (wpos >> 3)*7 + n7;
        if (hp < 4) {                 // zero-padded rows (wave-uniform)
            #pragma unroll
            for (int j=0;j<6;j++) orow[lane + 64*j] = 0;
            return;
        }
        const int wp = (wpos & 7)*7 + (n - n7*7);
        int h = hp - 1; if (h >= 52) h -= 52;   // (hp-4+3) % 52
        int w = wp + 3; if (w >= 56) w -= 56;
        xr = x + (((size_t)b*52 + h)*56 + w)*384;
    } else {
        xr = x + (size_t)row*384;
    }
    float v[6]; float sum = 0.f;
    #pragma unroll
    for (int j=0;j<6;j++){ v[j] = xr[lane + 64*j]; sum += v[j]; }
    #pragma unroll
    for (int m=1;m<64;m<<=1) sum += __shfl_xor(sum, m);
    const float mean = sum * (1.f/384.f);
    float var = 0.f;
    #pragma unroll
    for (int j=0;j<6;j++){ float d = v[j]-mean; var += d*d; }
    #pragma unroll
    for (int m=1;m<64;m<<=1) var += __shfl_xor(var, m);
    const float rstd = rsqrtf(var*(1.f/384.f) + 1e-5f);
    #pragma unroll
    for (int j=0;j<6;j++){
        const int c = lane + 64*j;
        orow[c] = f2b((v[j]-mean)*rstd*g[c] + bt[c]);
    }
}

// ---- generic bf16 GEMM (round-2 proven body): out = A @ Bt^T + bias ----
// EPI 0: +bias -> bf16      EPI 2: gelu(+bias) -> bf16
// EPI 1: +bias +x(shortcut) with inverse-window scatter -> f32 x1
// EPI 3: +bias +x1 -> f32 (in-place on x1)
template<int EPI>
__global__ __launch_bounds__(256, 2)
void gemm_kernel(const u16* __restrict__ A, const u16* __restrict__ Bt,
                 const float* __restrict__ bias, void* __restrict__ outp,
                 const float* __restrict__ extra, int M, int N, int K)
{
    (void)M;
    __shared__ u16 Als[2][4096];
    __shared__ u16 Bls[2][4096];
    const int tid = threadIdx.x;
    const int lane = tid & 63;
    const int wid = tid >> 6;
    const int wr = wid >> 1, wc = wid & 1;
    const int r16 = lane & 15, kc = lane >> 4;
    const int m0 = blockIdx.y*128, n0 = blockIdx.x*128;
    const int srow = tid >> 2, schunk = tid & 3;
    const int nk = K >> 5;

    // source-chunk XOR swizzle keeps LDS dest linear (tid*16B) but spreads banks
    const u16* Ab = A  + (size_t)(m0 + srow)*K + (schunk ^ ((srow >> 1) & 3))*8;
    const u16* Bb = Bt + (size_t)(n0 + srow)*K + (schunk ^ ((srow >> 1) & 3))*8;
    const size_t rskip = (size_t)64*K;

    gload16(Ab,         &Als[0][tid*8]);
    gload16(Ab + rskip, &Als[0][2048 + tid*8]);
    gload16(Bb,         &Bls[0][tid*8]);
    gload16(Bb + rskip, &Bls[0][2048 + tid*8]);

    f32x4 acc[4][4] = {};
    const int swz = (kc ^ ((r16 >> 1) & 3))*8;
    for (int kt = 0; kt < nk; ++kt) {
        __syncthreads();
        if (kt + 1 < nk) {
            const int buf = (kt + 1) & 1;
            const u16* a = Ab + (kt+1)*32;
            const u16* b = Bb + (kt+1)*32;
            gload16(a,         &Als[buf][tid*8]);
            gload16(a + rskip, &Als[buf][2048 + tid*8]);
            gload16(b,         &Bls[buf][tid*8]);
            gload16(b + rskip, &Bls[buf][2048 + tid*8]);
        }
        const u16* as = Als[kt & 1];
        const u16* bs = Bls[kt & 1];
        s16x8 af[4], bfr[4];
        #pragma unroll
        for (int i=0;i<4;i++) {
            af[i]  = *(const s16x8*)&as[(64*wr + 16*i + r16)*32 + swz];
            bfr[i] = *(const s16x8*)&bs[(64*wc + 16*i + r16)*32 + swz];
        }
        #pragma unroll
        for (int i=0;i<4;i++)
            #pragma unroll
            for (int j=0;j<4;j++)
                mfma_bf16(acc[i][j], af[i], bfr[j]);
    }

    float bj[4];
    #pragma unroll
    for (int j=0;j<4;j++) bj[j] = bias[n0 + 64*wc + 16*j + r16];

    if constexpr (EPI == 0 || EPI == 2) {
        u16* out = (u16*)outp;
        #pragma unroll
        for (int i=0;i<4;i++)
          #pragma unroll
          for (int r=0;r<4;r++) {
            const size_t row = m0 + 64*wr + 16*i + 4*kc + r;
            #pragma unroll
            for (int j=0;j<4;j++) {
                const int col = n0 + 64*wc + 16*j + r16;
                float v = acc[i][j][r] + bj[j];
                if constexpr (EPI == 2) v = 0.5f*v*(1.f + erff(v*0.70710678118f));
                out[row*(size_t)N + col] = f2b(v);
            }
          }
    } else if constexpr (EPI == 3) {
        float* out = (float*)outp;
        #pragma unroll
        for (int i=0;i<4;i++)
          #pragma unroll
          for (int r=0;r<4;r++) {
            const size_t row = m0 + 64*wr + 16*i + 4*kc + r;
            #pragma unroll
            for (int j=0;j<4;j++) {
                const int col = n0 + 64*wc + 16*j + r16;
                out[row*(size_t)N + col] = extra[row*(size_t)N + col] + acc[i][j][r] + bj[j];
            }
          }
    } else { // EPI == 1
        float* out = (float*)outp;
        #pragma unroll
        for (int i=0;i<4;i++)
          #pragma unroll
          for (int r=0;r<4;r++) {
            const int row = m0 + 64*wr + 16*i + 4*kc + r;
            const int win = row / 49, n = row - win*49;
            const int wpos = win & 63, b = win >> 6;
            const int n7 = n / 7;
            const int hp = (wpos >> 3)*7 + n7;
            if (hp < 4) continue;               // dropped padded rows
            const int wp = (wpos & 7)*7 + (n - n7*7);
            int h = hp + 2; if (h >= 52) h -= 52;   // (hp-4+6) % 52
            int w = wp + 6; if (w >= 56) w -= 56;
            const size_t base = (((size_t)b*52 + h)*56 + w)*384;
            #pragma unroll
            for (int j=0;j<4;j++) {
                const int col = n0 + 64*wc + 16*j + r16;
                out[base + col] = extra[base + col] + acc[i][j][r] + bj[j];
            }
          }
    }
}

// ---- scalar-exact windowed attention (R2-proven math, vectorized I/O) ----
// Lane r (<49) owns output row r. K/V staged bf16 in LDS; fp32 math;
// exact 49-wide softmax via per-wave LDS score rows.
__global__ __launch_bounds__(256, 2)
void attn_scalar(const u16* __restrict__ qkvc, const float* __restrict__ cm,
                 u16* __restrict__ o, int win_base)
{
    __shared__ __align__(16) u16 Kls[4][1568];
    __shared__ __align__(16) u16 Vls[4][1568];
    __shared__ float Sls[4][2401];
    const int tid = threadIdx.x, lane = tid & 63, wv = tid >> 6;
    const int u = blockIdx.x*4 + wv;
    const int wloc = u / 12, head = u - wloc*12;
    const int wglob = win_base + wloc;
    const int wpos = wglob & 63;
    const u16* base = qkvc + (size_t)wloc*49*1152 + head*32;

    // stage K,V: 196 x 16B vector copies each (same layout as R2's scalar loop)
    for (int i = lane; i < 196; i += 64) {
        const int row = i >> 2, dv = (i & 3) * 8;
        *(s16x8*)&Kls[wv][row*32 + dv] = *(const s16x8*)&base[(size_t)row*1152 + 384 + dv];
        *(s16x8*)&Vls[wv][row*32 + dv] = *(const s16x8*)&base[(size_t)row*1152 + 768 + dv];
    }
    __syncthreads();

    const int r = lane;
    if (r < 49) {
        float q[32];
        const u16* qp = base + (size_t)r*1152;
        #pragma unroll
        for (int d = 0; d < 32; ++d) q[d] = b2f(qp[d]) * SCALE_F;
        const float* cmb = cm + ((size_t)wpos*12 + head)*2401 + r*49;
        const u16* kw = Kls[wv];
        float* sw = Sls[wv] + r*49;
        float mx = -1e30f;
        for (int c = 0; c < 49; ++c) {
            float s = 0.f;
            #pragma unroll
            for (int d = 0; d < 32; ++d) s += q[d]*b2f(kw[c*32+d]);
            s += cmb[c];
            sw[c] = s;
            mx = fmaxf(mx, s);
        }
        float sm = 0.f;
        for (int c = 0; c < 49; ++c) { float e = __expf(sw[c]-mx); sm += e; sw[c] = e; }
        const float inv = 1.f/sm;
        float oa[32];
        #pragma unroll
        for (int d = 0; d < 32; ++d) oa[d] = 0.f;
        const u16* vw = Vls[wv];
        for (int c = 0; c < 49; ++c) {
            const float p = sw[c]*inv;
            #pragma unroll
            for (int d = 0; d < 32; ++d) oa[d] += p*b2f(vw[c*32+d]);
        }
        u16* op = o + (size_t)(wglob*49 + r)*384 + head*32;
        #pragma unroll
        for (int v8 = 0; v8 < 4; ++v8) {
            s16x8 pk;
            #pragma unroll
            for (int jj = 0; jj < 8; ++jj) pk[jj] = (short)f2b(oa[v8*8+jj]);
            *(s16x8*)&op[v8*8] = pk;
        }
    }
}

static int pick_chunks(size_t full, size_t avail) {
    for (int n = 1; n <= 8; n <<= 1) if (full / n <= avail) return n;
    return 8;   // R2-proven fallback (ws >= 204MB demonstrated)
}

extern "C" void kernel_launch(void* const* d_in, const int* in_sizes, int n_in,
                              void* d_out, int out_size, void* d_ws, size_t ws_size,
                              hipStream_t stream)
{
    (void)in_sizes; (void)n_in; (void)out_size;
    const float* x      = (const float*)d_in[0];
    const float* n1g    = (const float*)d_in[1];
    const float* n1b    = (const float*)d_in[2];
    const float* qkv_w  = (const float*)d_in[3];
    const float* qkv_b  = (const float*)d_in[4];
    const float* rpb    = (const float*)d_in[5];
    const float* proj_w = (const float*)d_in[6];
    const float* proj_b = (const float*)d_in[7];
    const float* n2g    = (const float*)d_in[8];
    const float* n2b    = (const float*)d_in[9];
    const float* fc1_w  = (const float*)d_in[10];
    const float* fc1_b  = (const float*)d_in[11];
    const float* fc2_w  = (const float*)d_in[12];
    const float* fc2_b  = (const float*)d_in[13];
    const float* amask  = (const float*)d_in[14];
    const float* pmask  = (const float*)d_in[15];
    const int*   ridx   = (const int*)d_in[16];

    char* ws = (char*)d_ws;
    float* cm    = (float*)(ws + OFF_CM);
    u16* wqkvT   = (u16*)(ws + OFF_WQ);
    u16* wprojT  = (u16*)(ws + OFF_WP);
    u16* wfc1T   = (u16*)(ws + OFF_W1);
    u16* wfc2T   = (u16*)(ws + OFF_W2);
    u16* awin    = (u16*)(ws + OFF_AWIN);
    u16* obuf    = (u16*)(ws + OFF_OBUF);
    u16* arena   = (u16*)(ws + OFF_ARENA);  // qkv chunk, later fc1 chunk
    u16* ln2o    = (u16*)(ws + OFF_AWIN);   // reuse (awin dead after QKV)
    float* x1    = (float*)d_out;           // x1 lives in d_out (in-place finish)

    const size_t avail = (ws_size > OFF_ARENA) ? ws_size - OFF_ARENA : 0;

    cm_kernel  <<<dim3(64,12),  256, 0, stream>>>(amask, pmask, rpb, ridx, cm);
    wconv_kernel<<<dim3(2,1152),256, 0, stream>>>(qkv_w,  wqkvT, 384, 1152);
    wconv_kernel<<<dim3(2,384), 256, 0, stream>>>(proj_w, wprojT, 384, 384);
    wconv_kernel<<<dim3(2,1536),256, 0, stream>>>(fc1_w,  wfc1T, 384, 1536);
    wconv_kernel<<<dim3(6,384), 256, 0, stream>>>(fc2_w,  wfc2T, 1536, 384);

    ln_kernel<1><<<25088, 256, 0, stream>>>(x, n1g, n1b, awin);

    // QKV + attention; chunked only if the arena is too small
    {
        const int n_attn = pick_chunks(QKV_FULL, avail);
        const int wchunk = 2048 / n_attn;          // windows per chunk
        const int rows_a = wchunk * 49;            // multiple of 128 for all n
        for (int c = 0; c < n_attn; ++c) {
            const u16* aA = awin + (size_t)c*rows_a*384;
            gemm_kernel<0><<<dim3(9, rows_a/128), 256, 0, stream>>>(
                aA, wqkvT, qkv_b, arena, nullptr, rows_a, 1152, 384);
            attn_scalar<<<wchunk*3, 256, 0, stream>>>(arena, cm, obuf, c*wchunk);
        }
    }

    gemm_kernel<1><<<dim3(3,784), 256, 0, stream>>>(obuf, wprojT, proj_b, x1, x, 100352, 384, 384);
    ln_kernel<0><<<23296, 256, 0, stream>>>(x1, n2g, n2b, ln2o);

    // MLP; chunked only if the arena is too small
    {
        const int n_mlp = pick_chunks(FC1_FULL, avail);
        const int rows_m = 93184 / n_mlp;          // 728/n blocks, n in {1,2,4,8}
        for (int c = 0; c < n_mlp; ++c) {
            const size_t ro = (size_t)c*rows_m;
            gemm_kernel<2><<<dim3(12, rows_m/128), 256, 0, stream>>>(
                ln2o + ro*384, wfc1T, fc1_b, arena, nullptr, rows_m, 1536, 384);
            gemm_kernel<3><<<dim3(3, rows_m/128), 256, 0, stream>>>(
                arena, wfc2T, fc2_b, x1 + ro*384, x1 + ro*384, rows_m, 384, 1536);
        }
    }
}

// Round 7
// 871.352 us; speedup vs baseline: 1.6514x; 1.2950x over previous
//
#include <hip/hip_runtime.h>
#include <hip/hip_bf16.h>

typedef unsigned short u16;
typedef short s16x8 __attribute__((ext_vector_type(8)));
typedef float f32x4 __attribute__((ext_vector_type(4)));
typedef __bf16 bf16x8 __attribute__((ext_vector_type(8)));

#define SCALE_F 0.17677669529663687f

// workspace layout (bytes). Fixed part ends at 168MB (R2/R6-proven); arena adaptive.
#define OFF_CM    ((size_t)0)                 // 64*12*2401*4 = 7,375,872
#define OFF_WQ    ((size_t)8<<20)             // qkvT  1152*384*2
#define OFF_WP    (OFF_WQ + 884736)           // projT 384*384*2
#define OFF_W1    (OFF_WP + 294912)           // fc1T  1536*384*2
#define OFF_W2    (OFF_W1 + 1179648)          // fc2T  384*1536*2
#define OFF_AWIN  ((size_t)12<<20)            // 77MB: A_win -> (reuse) ln2o
#define OFF_OBUF  ((size_t)90<<20)            // 73.5MB: attention output
#define OFF_ARENA ((size_t)168<<20)           // qkv chunk / fc1 chunk (adaptive)

#define QKV_FULL  ((size_t)100352*1152*2)     // 231,211,008
#define FC1_FULL  ((size_t)93184*1536*2)      // 286,261,248

static __device__ __forceinline__ u16 f2b(float f) {
    unsigned u = __float_as_uint(f);
    u += 0x7fffu + ((u >> 16) & 1u);
    return (u16)(u >> 16);
}
static __device__ __forceinline__ float b2f(u16 u) {
    return __uint_as_float((unsigned)u << 16);
}

union frag_u { s16x8 s; bf16x8 b; };
static __device__ __forceinline__ bf16x8 tob(s16x8 v) { frag_u u; u.s = v; return u.b; }

static __device__ __forceinline__ void mfma_bf16(f32x4& d, s16x8 a, s16x8 b) {
    asm("v_mfma_f32_16x16x32_bf16 %0, %1, %2, %0" : "+v"(d) : "v"(a), "v"(b));
}

static __device__ __forceinline__ void gload16(const void* g, void* l) {
    __builtin_amdgcn_global_load_lds(
        (const __attribute__((address_space(1))) unsigned int*)g,
        (__attribute__((address_space(3))) unsigned int*)l, 16, 0, 0);
}

// ---- combined mask+bias: CM[wpos][head][r*49+c] ----
__global__ void cm_kernel(const float* __restrict__ am, const float* __restrict__ pm,
                          const float* __restrict__ rpb, const int* __restrict__ ridx,
                          float* __restrict__ cmo)
{
    const int wpos = blockIdx.x, head = blockIdx.y;
    float* o = cmo + ((size_t)wpos*12 + head)*2401;
    const float* a = am + (size_t)wpos*2401;
    const float* p = pm + (size_t)wpos*2401;
    for (int e = threadIdx.x; e < 2401; e += 256)
        o[e] = a[e] + p[e] + rpb[ridx[e]*12 + head];
}

// ---- weight transpose+convert: Wt[n][k] = bf16(W[k][n]) ----
__global__ void wconv_kernel(const float* __restrict__ w, u16* __restrict__ wt,
                             int K, int N)
{
    const int k = blockIdx.x*256 + threadIdx.x;
    const int n = blockIdx.y;
    if (k < K) wt[(size_t)n*K + k] = f2b(w[(size_t)k*N + n]);
}

// ---- layernorm; WINDOWED=1 adds roll/pad/window-partition gather ----
template<int WINDOWED>
__global__ __launch_bounds__(256, 4)
void ln_kernel(const float* __restrict__ x, const float* __restrict__ g,
               const float* __restrict__ bt, u16* __restrict__ out)
{
    const int lane = threadIdx.x & 63;
    const int row = blockIdx.x*4 + (threadIdx.x >> 6);
    u16* orow = out + (size_t)row*384;
    const float* xr;
    if (WINDOWED) {
        const int win = row / 49, n = row - win*49;
        const int wpos = win & 63, b = win >> 6;
        const int n7 = n / 7;
        const int hp = (wpos >> 3)*7 + n7;
        if (hp < 4) {                 // zero-padded rows (wave-uniform)
            #pragma unroll
            for (int j=0;j<6;j++) orow[lane + 64*j] = 0;
            return;
        }
        const int wp = (wpos & 7)*7 + (n - n7*7);
        int h = hp - 1; if (h >= 52) h -= 52;   // (hp-4+3) % 52
        int w = wp + 3; if (w >= 56) w -= 56;
        xr = x + (((size_t)b*52 + h)*56 + w)*384;
    } else {
        xr = x + (size_t)row*384;
    }
    float v[6]; float sum = 0.f;
    #pragma unroll
    for (int j=0;j<6;j++){ v[j] = xr[lane + 64*j]; sum += v[j]; }
    #pragma unroll
    for (int m=1;m<64;m<<=1) sum += __shfl_xor(sum, m);
    const float mean = sum * (1.f/384.f);
    float var = 0.f;
    #pragma unroll
    for (int j=0;j<6;j++){ float d = v[j]-mean; var += d*d; }
    #pragma unroll
    for (int m=1;m<64;m<<=1) var += __shfl_xor(var, m);
    const float rstd = rsqrtf(var*(1.f/384.f) + 1e-5f);
    #pragma unroll
    for (int j=0;j<6;j++){
        const int c = lane + 64*j;
        orow[c] = f2b((v[j]-mean)*rstd*g[c] + bt[c]);
    }
}

// ---- generic bf16 GEMM (proven body): out = A @ Bt^T + bias ----
// EPI 0: +bias -> bf16      EPI 2: gelu(+bias) -> bf16
// EPI 1: +bias +x(shortcut) with inverse-window scatter -> f32 x1
// EPI 3: +bias +x1 -> f32 (in-place on x1)
template<int EPI>
__global__ __launch_bounds__(256, 2)
void gemm_kernel(const u16* __restrict__ A, const u16* __restrict__ Bt,
                 const float* __restrict__ bias, void* __restrict__ outp,
                 const float* __restrict__ extra, int M, int N, int K)
{
    (void)M;
    __shared__ u16 Als[2][4096];
    __shared__ u16 Bls[2][4096];
    const int tid = threadIdx.x;
    const int lane = tid & 63;
    const int wid = tid >> 6;
    const int wr = wid >> 1, wc = wid & 1;
    const int r16 = lane & 15, kc = lane >> 4;
    const int m0 = blockIdx.y*128, n0 = blockIdx.x*128;
    const int srow = tid >> 2, schunk = tid & 3;
    const int nk = K >> 5;

    // source-chunk XOR swizzle keeps LDS dest linear (tid*16B) but spreads banks
    const u16* Ab = A  + (size_t)(m0 + srow)*K + (schunk ^ ((srow >> 1) & 3))*8;
    const u16* Bb = Bt + (size_t)(n0 + srow)*K + (schunk ^ ((srow >> 1) & 3))*8;
    const size_t rskip = (size_t)64*K;

    gload16(Ab,         &Als[0][tid*8]);
    gload16(Ab + rskip, &Als[0][2048 + tid*8]);
    gload16(Bb,         &Bls[0][tid*8]);
    gload16(Bb + rskip, &Bls[0][2048 + tid*8]);

    f32x4 acc[4][4] = {};
    const int swz = (kc ^ ((r16 >> 1) & 3))*8;
    for (int kt = 0; kt < nk; ++kt) {
        __syncthreads();
        if (kt + 1 < nk) {
            const int buf = (kt + 1) & 1;
            const u16* a = Ab + (kt+1)*32;
            const u16* b = Bb + (kt+1)*32;
            gload16(a,         &Als[buf][tid*8]);
            gload16(a + rskip, &Als[buf][2048 + tid*8]);
            gload16(b,         &Bls[buf][tid*8]);
            gload16(b + rskip, &Bls[buf][2048 + tid*8]);
        }
        const u16* as = Als[kt & 1];
        const u16* bs = Bls[kt & 1];
        s16x8 af[4], bfr[4];
        #pragma unroll
        for (int i=0;i<4;i++) {
            af[i]  = *(const s16x8*)&as[(64*wr + 16*i + r16)*32 + swz];
            bfr[i] = *(const s16x8*)&bs[(64*wc + 16*i + r16)*32 + swz];
        }
        #pragma unroll
        for (int i=0;i<4;i++)
            #pragma unroll
            for (int j=0;j<4;j++)
                mfma_bf16(acc[i][j], af[i], bfr[j]);
    }

    float bj[4];
    #pragma unroll
    for (int j=0;j<4;j++) bj[j] = bias[n0 + 64*wc + 16*j + r16];

    if constexpr (EPI == 0 || EPI == 2) {
        u16* out = (u16*)outp;
        #pragma unroll
        for (int i=0;i<4;i++)
          #pragma unroll
          for (int r=0;r<4;r++) {
            const size_t row = m0 + 64*wr + 16*i + 4*kc + r;
            #pragma unroll
            for (int j=0;j<4;j++) {
                const int col = n0 + 64*wc + 16*j + r16;
                float v = acc[i][j][r] + bj[j];
                if constexpr (EPI == 2) v = 0.5f*v*(1.f + erff(v*0.70710678118f));
                out[row*(size_t)N + col] = f2b(v);
            }
          }
    } else if constexpr (EPI == 3) {
        float* out = (float*)outp;
        #pragma unroll
        for (int i=0;i<4;i++)
          #pragma unroll
          for (int r=0;r<4;r++) {
            const size_t row = m0 + 64*wr + 16*i + 4*kc + r;
            #pragma unroll
            for (int j=0;j<4;j++) {
                const int col = n0 + 64*wc + 16*j + r16;
                out[row*(size_t)N + col] = extra[row*(size_t)N + col] + acc[i][j][r] + bj[j];
            }
          }
    } else { // EPI == 1
        float* out = (float*)outp;
        #pragma unroll
        for (int i=0;i<4;i++)
          #pragma unroll
          for (int r=0;r<4;r++) {
            const int row = m0 + 64*wr + 16*i + 4*kc + r;
            const int win = row / 49, n = row - win*49;
            const int wpos = win & 63, b = win >> 6;
            const int n7 = n / 7;
            const int hp = (wpos >> 3)*7 + n7;
            if (hp < 4) continue;               // dropped padded rows
            const int wp = (wpos & 7)*7 + (n - n7*7);
            int h = hp + 2; if (h >= 52) h -= 52;   // (hp-4+6) % 52
            int w = wp + 6; if (w >= 56) w -= 56;
            const size_t base = (((size_t)b*52 + h)*56 + w)*384;
            #pragma unroll
            for (int j=0;j<4;j++) {
                const int col = n0 + 64*wc + 16*j + r16;
                out[base + col] = extra[base + col] + acc[i][j][r] + bj[j];
            }
          }
    }
}

// ---- MFMA attention v2: builtin MFMA + PROVEN scalar softmax via LDS ----
// 1 wave per (window, head). Fragment conventions = validated gemm core:
//   A-frag lane(r16,kc) elem jj = A[16i+r16][kc*8+jj]
//   B-frag lane(r16,kc) elem jj = B[kc*8+jj][16j+r16]
//   C     lane(r16,kc) reg r    = C[16i+4kc+r][16j+r16]
// S (f32, stride 49) and P (bf16, stride 72) share one per-wave LDS region;
// barriers separate the phases (cross-type aliasing => explicit ordering).
__global__ __launch_bounds__(256, 2)
void attn_mfma2(const u16* __restrict__ qkvc, const float* __restrict__ cm,
                u16* __restrict__ o, int win_base)
{
    __shared__ float Sls[4][2432];    // 9728 B per wave
    const int tid = threadIdx.x, lane = tid & 63, wv = tid >> 6;
    const int u = blockIdx.x*4 + wv;
    const int wloc = u / 12, head = u - wloc*12;
    const int wglob = win_base + wloc;
    const int wpos = wglob & 63;
    const int r16 = lane & 15, kc = lane >> 4;
    const u16* base = qkvc + (size_t)wloc*49*1152 + head*32;

    // Q,K fragments (rows padded with zeros beyond 48)
    bf16x8 qf[4], kf[4];
    #pragma unroll
    for (int i=0;i<4;i++) {
        const int row = 16*i + r16;
        s16x8 qv = {}, kv = {};
        if (row < 49) {
            const u16* p = base + (size_t)row*1152 + kc*8;
            qv = *(const s16x8*)p;
            kv = *(const s16x8*)(p + 384);
        }
        qf[i] = tob(qv); kf[i] = tob(kv);
    }

    // S = Q@K^T (K-dim = 32 = one MFMA step), scaled + mask, into LDS f32
    float* sw = Sls[wv];
    const float* cmb = cm + ((size_t)wpos*12 + head)*2401;
    #pragma unroll
    for (int i=0;i<4;i++)
      #pragma unroll
      for (int j=0;j<4;j++) {
        f32x4 s = {};
        s = __builtin_amdgcn_mfma_f32_16x16x32_bf16(qf[i], kf[j], s, 0, 0, 0);
        #pragma unroll
        for (int r=0;r<4;r++) {
            const int row = 16*i + 4*kc + r;
            const int col = 16*j + r16;
            if (row < 49 && col < 49)
                sw[row*49 + col] = s[r]*SCALE_F + cmb[row*49 + col];
        }
      }
    __syncthreads();

    // softmax: proven scalar pattern — lane r owns row r, all fp32
    float e[49]; float inv = 0.f;
    const int r = lane;
    if (r < 49) {
        #pragma unroll
        for (int c=0;c<49;c++) e[c] = sw[r*49 + c];
        float mx = -1e30f;
        #pragma unroll
        for (int c=0;c<49;c++) mx = fmaxf(mx, e[c]);
        float sm = 0.f;
        #pragma unroll
        for (int c=0;c<49;c++){ e[c] = __expf(e[c]-mx); sm += e[c]; }
        inv = 1.f/sm;
    }
    __syncthreads();   // all S reads complete before the P overlay is written

    // P (bf16, stride 72, cols 49..63 zeroed) overlays the S region
    u16* pw = (u16*)sw;
    if (r < 49) {
        #pragma unroll
        for (int w8 = 0; w8 < 8; ++w8) {
            s16x8 pk = {};
            #pragma unroll
            for (int jj=0;jj<8;jj++) {
                const int c = w8*8 + jj;
                if (c < 49) pk[jj] = (short)f2b(e[c]*inv);
            }
            *(s16x8*)&pw[r*72 + w8*8] = pk;
        }
    }
    __syncthreads();

    // V in B-fragment layout (k>48 clamped to row 0; multiplied by P==0)
    bf16x8 vf[2][2];
    const u16* vb = base + 768;
    #pragma unroll
    for (int kk=0;kk<2;kk++)
      #pragma unroll
      for (int jn=0;jn<2;jn++) {
        s16x8 vv;
        #pragma unroll
        for (int jj=0;jj<8;jj++) {
            int k = 32*kk + 8*kc + jj;
            if (k > 48) k = 0;
            vv[jj] = (short)vb[(size_t)k*1152 + 16*jn + r16];
        }
        vf[kk][jn] = tob(vv);
      }

    // O = P @ V
    f32x4 oa[4][2] = {};
    #pragma unroll
    for (int i=0;i<4;i++)
      #pragma unroll
      for (int kk=0;kk<2;kk++) {
        const bf16x8 pa = tob(*(const s16x8*)&pw[(16*i + r16)*72 + 32*kk + kc*8]);
        #pragma unroll
        for (int jn=0;jn<2;jn++)
            oa[i][jn] = __builtin_amdgcn_mfma_f32_16x16x32_bf16(pa, vf[kk][jn], oa[i][jn], 0, 0, 0);
      }

    #pragma unroll
    for (int i=0;i<4;i++)
      #pragma unroll
      for (int rr=0;rr<4;rr++) {
        const int row = 16*i + 4*kc + rr;
        if (row < 49) {
          #pragma unroll
          for (int jn=0;jn<2;jn++)
            o[(size_t)(wglob*49 + row)*384 + head*32 + 16*jn + r16] = f2b(oa[i][jn][rr]);
        }
      }
}

static int pick_chunks(size_t full, size_t avail) {
    for (int n = 1; n <= 8; n <<= 1) if (full / n <= avail) return n;
    return 8;   // R2-proven fallback (ws >= 204MB demonstrated)
}

extern "C" void kernel_launch(void* const* d_in, const int* in_sizes, int n_in,
                              void* d_out, int out_size, void* d_ws, size_t ws_size,
                              hipStream_t stream)
{
    (void)in_sizes; (void)n_in; (void)out_size;
    const float* x      = (const float*)d_in[0];
    const float* n1g    = (const float*)d_in[1];
    const float* n1b    = (const float*)d_in[2];
    const float* qkv_w  = (const float*)d_in[3];
    const float* qkv_b  = (const float*)d_in[4];
    const float* rpb    = (const float*)d_in[5];
    const float* proj_w = (const float*)d_in[6];
    const float* proj_b = (const float*)d_in[7];
    const float* n2g    = (const float*)d_in[8];
    const float* n2b    = (const float*)d_in[9];
    const float* fc1_w  = (const float*)d_in[10];
    const float* fc1_b  = (const float*)d_in[11];
    const float* fc2_w  = (const float*)d_in[12];
    const float* fc2_b  = (const float*)d_in[13];
    const float* amask  = (const float*)d_in[14];
    const float* pmask  = (const float*)d_in[15];
    const int*   ridx   = (const int*)d_in[16];

    char* ws = (char*)d_ws;
    float* cm    = (float*)(ws + OFF_CM);
    u16* wqkvT   = (u16*)(ws + OFF_WQ);
    u16* wprojT  = (u16*)(ws + OFF_WP);
    u16* wfc1T   = (u16*)(ws + OFF_W1);
    u16* wfc2T   = (u16*)(ws + OFF_W2);
    u16* awin    = (u16*)(ws + OFF_AWIN);
    u16* obuf    = (u16*)(ws + OFF_OBUF);
    u16* arena   = (u16*)(ws + OFF_ARENA);  // qkv chunk, later fc1 chunk
    u16* ln2o    = (u16*)(ws + OFF_AWIN);   // reuse (awin dead after QKV)
    float* x1    = (float*)d_out;           // x1 lives in d_out (in-place finish)

    const size_t avail = (ws_size > OFF_ARENA) ? ws_size - OFF_ARENA : 0;

    cm_kernel  <<<dim3(64,12),  256, 0, stream>>>(amask, pmask, rpb, ridx, cm);
    wconv_kernel<<<dim3(2,1152),256, 0, stream>>>(qkv_w,  wqkvT, 384, 1152);
    wconv_kernel<<<dim3(2,384), 256, 0, stream>>>(proj_w, wprojT, 384, 384);
    wconv_kernel<<<dim3(2,1536),256, 0, stream>>>(fc1_w,  wfc1T, 384, 1536);
    wconv_kernel<<<dim3(6,384), 256, 0, stream>>>(fc2_w,  wfc2T, 1536, 384);

    ln_kernel<1><<<25088, 256, 0, stream>>>(x, n1g, n1b, awin);

    // QKV + attention; chunked only if the arena is too small
    {
        const int n_attn = pick_chunks(QKV_FULL, avail);
        const int wchunk = 2048 / n_attn;          // windows per chunk
        const int rows_a = wchunk * 49;            // multiple of 128 for all n
        for (int c = 0; c < n_attn; ++c) {
            const u16* aA = awin + (size_t)c*rows_a*384;
            gemm_kernel<0><<<dim3(9, rows_a/128), 256, 0, stream>>>(
                aA, wqkvT, qkv_b, arena, nullptr, rows_a, 1152, 384);
            attn_mfma2<<<wchunk*3, 256, 0, stream>>>(arena, cm, obuf, c*wchunk);
        }
    }

    gemm_kernel<1><<<dim3(3,784), 256, 0, stream>>>(obuf, wprojT, proj_b, x1, x, 100352, 384, 384);
    ln_kernel<0><<<23296, 256, 0, stream>>>(x1, n2g, n2b, ln2o);

    // MLP; chunked only if the arena is too small
    {
        const int n_mlp = pick_chunks(FC1_FULL, avail);
        const int rows_m = 93184 / n_mlp;          // 728/n blocks, n in {1,2,4,8}
        for (int c = 0; c < n_mlp; ++c) {
            const size_t ro = (size_t)c*rows_m;
            gemm_kernel<2><<<dim3(12, rows_m/128), 256, 0, stream>>>(
                ln2o + ro*384, wfc1T, fc1_b, arena, nullptr, rows_m, 1536, 384);
            gemm_kernel<3><<<dim3(3, rows_m/128), 256, 0, stream>>>(
                arena, wfc2T, fc2_b, x1 + ro*384, x1 + ro*384, rows_m, 384, 1536);
        }
    }
}

// Round 8
// 834.022 us; speedup vs baseline: 1.7254x; 1.0448x over previous
//
#include <hip/hip_runtime.h>
#include <hip/hip_bf16.h>

typedef unsigned short u16;
typedef short s16x8 __attribute__((ext_vector_type(8)));
typedef float f32x4 __attribute__((ext_vector_type(4)));
typedef __bf16 bf16x8 __attribute__((ext_vector_type(8)));

#define SCALE_F 0.17677669529663687f

// workspace layout (bytes). Fixed part ends at 168MB (R2/R6-proven); arena adaptive.
#define OFF_CM    ((size_t)0)                 // 64*12*2401*4 = 7,375,872
#define OFF_WQ    ((size_t)8<<20)             // qkvT  1152*384*2
#define OFF_WP    (OFF_WQ + 884736)           // projT 384*384*2
#define OFF_W1    (OFF_WP + 294912)           // fc1T  1536*384*2
#define OFF_W2    (OFF_W1 + 1179648)          // fc2T  384*1536*2
#define OFF_AWIN  ((size_t)12<<20)            // 77MB: A_win -> (reuse) ln2o
#define OFF_OBUF  ((size_t)90<<20)            // 73.5MB: attention output
#define OFF_ARENA ((size_t)168<<20)           // qkv chunk / fc1 chunk (adaptive)

#define QKV_FULL  ((size_t)100352*1152*2)     // 231,211,008
#define FC1_FULL  ((size_t)93184*1536*2)      // 286,261,248

static __device__ __forceinline__ u16 f2b(float f) {
    unsigned u = __float_as_uint(f);
    u += 0x7fffu + ((u >> 16) & 1u);
    return (u16)(u >> 16);
}
static __device__ __forceinline__ float b2f(u16 u) {
    return __uint_as_float((unsigned)u << 16);
}

union frag_u { s16x8 s; bf16x8 b; };
static __device__ __forceinline__ bf16x8 tob(s16x8 v) { frag_u u; u.s = v; return u.b; }

static __device__ __forceinline__ void mfma_bf16(f32x4& d, s16x8 a, s16x8 b) {
    asm("v_mfma_f32_16x16x32_bf16 %0, %1, %2, %0" : "+v"(d) : "v"(a), "v"(b));
}

static __device__ __forceinline__ void gload16(const void* g, void* l) {
    __builtin_amdgcn_global_load_lds(
        (const __attribute__((address_space(1))) unsigned int*)g,
        (__attribute__((address_space(3))) unsigned int*)l, 16, 0, 0);
}

// ---- combined mask+bias: CM[wpos][head][r*49+c] ----
__global__ void cm_kernel(const float* __restrict__ am, const float* __restrict__ pm,
                          const float* __restrict__ rpb, const int* __restrict__ ridx,
                          float* __restrict__ cmo)
{
    const int wpos = blockIdx.x, head = blockIdx.y;
    float* o = cmo + ((size_t)wpos*12 + head)*2401;
    const float* a = am + (size_t)wpos*2401;
    const float* p = pm + (size_t)wpos*2401;
    for (int e = threadIdx.x; e < 2401; e += 256)
        o[e] = a[e] + p[e] + rpb[ridx[e]*12 + head];
}

// ---- weight transpose+convert: Wt[n][k] = bf16(W[k][n]) ----
__global__ void wconv_kernel(const float* __restrict__ w, u16* __restrict__ wt,
                             int K, int N)
{
    const int k = blockIdx.x*256 + threadIdx.x;
    const int n = blockIdx.y;
    if (k < K) wt[(size_t)n*K + k] = f2b(w[(size_t)k*N + n]);
}

// ---- layernorm; WINDOWED=1 adds roll/pad/window-partition gather ----
template<int WINDOWED>
__global__ __launch_bounds__(256, 4)
void ln_kernel(const float* __restrict__ x, const float* __restrict__ g,
               const float* __restrict__ bt, u16* __restrict__ out)
{
    const int lane = threadIdx.x & 63;
    const int row = blockIdx.x*4 + (threadIdx.x >> 6);
    u16* orow = out + (size_t)row*384;
    const float* xr;
    if (WINDOWED) {
        const int win = row / 49, n = row - win*49;
        const int wpos = win & 63, b = win >> 6;
        const int n7 = n / 7;
        const int hp = (wpos >> 3)*7 + n7;
        if (hp < 4) {                 // zero-padded rows (wave-uniform)
            #pragma unroll
            for (int j=0;j<6;j++) orow[lane + 64*j] = 0;
            return;
        }
        const int wp = (wpos & 7)*7 + (n - n7*7);
        int h = hp - 1; if (h >= 52) h -= 52;   // (hp-4+3) % 52
        int w = wp + 3; if (w >= 56) w -= 56;
        xr = x + (((size_t)b*52 + h)*56 + w)*384;
    } else {
        xr = x + (size_t)row*384;
    }
    float v[6]; float sum = 0.f;
    #pragma unroll
    for (int j=0;j<6;j++){ v[j] = xr[lane + 64*j]; sum += v[j]; }
    #pragma unroll
    for (int m=1;m<64;m<<=1) sum += __shfl_xor(sum, m);
    const float mean = sum * (1.f/384.f);
    float var = 0.f;
    #pragma unroll
    for (int j=0;j<6;j++){ float d = v[j]-mean; var += d*d; }
    #pragma unroll
    for (int m=1;m<64;m<<=1) var += __shfl_xor(var, m);
    const float rstd = rsqrtf(var*(1.f/384.f) + 1e-5f);
    #pragma unroll
    for (int j=0;j<6;j++){
        const int c = lane + 64*j;
        orow[c] = f2b((v[j]-mean)*rstd*g[c] + bt[c]);
    }
}

// ---- generic bf16 GEMM (proven body + bijective XCD swizzle): ----
// out[M][N] = A[M][K] @ Bt[N][K]^T + bias
// EPI 0: +bias -> bf16      EPI 2: gelu(+bias) -> bf16
// EPI 1: +bias +x(shortcut) with inverse-window scatter -> f32 x1
// EPI 3: +bias +x1 -> f32 (in-place on x1)
template<int EPI>
__global__ __launch_bounds__(256, 2)
void gemm_kernel(const u16* __restrict__ A, const u16* __restrict__ Bt,
                 const float* __restrict__ bias, void* __restrict__ outp,
                 const float* __restrict__ extra, int M, int N, int K)
{
    (void)M;
    __shared__ u16 Als[2][4096];
    __shared__ u16 Bls[2][4096];
    const int tid = threadIdx.x;
    const int lane = tid & 63;
    const int wid = tid >> 6;
    const int wr = wid >> 1, wc = wid & 1;
    const int r16 = lane & 15, kc = lane >> 4;

    // bijective XCD swizzle (m204): contiguous flat-block ranges -> one XCD,
    // so the gx blocks sharing an A-panel hit the same L2.
    const int gx = gridDim.x;
    const int nwg = gx * gridDim.y;
    const int flat = blockIdx.y*gx + blockIdx.x;
    const int q8 = nwg >> 3, r8 = nwg & 7;
    const int xcd = flat & 7, idx = flat >> 3;
    const int tile = (xcd < r8 ? xcd*(q8+1) : r8*(q8+1) + (xcd-r8)*q8) + idx;
    const int ty = tile / gx;
    const int m0 = ty*128, n0 = (tile - ty*gx)*128;

    const int srow = tid >> 2, schunk = tid & 3;
    const int nk = K >> 5;

    // source-chunk XOR swizzle keeps LDS dest linear (tid*16B) but spreads banks
    const u16* Ab = A  + (size_t)(m0 + srow)*K + (schunk ^ ((srow >> 1) & 3))*8;
    const u16* Bb = Bt + (size_t)(n0 + srow)*K + (schunk ^ ((srow >> 1) & 3))*8;
    const size_t rskip = (size_t)64*K;

    gload16(Ab,         &Als[0][tid*8]);
    gload16(Ab + rskip, &Als[0][2048 + tid*8]);
    gload16(Bb,         &Bls[0][tid*8]);
    gload16(Bb + rskip, &Bls[0][2048 + tid*8]);

    f32x4 acc[4][4] = {};
    const int swz = (kc ^ ((r16 >> 1) & 3))*8;
    for (int kt = 0; kt < nk; ++kt) {
        __syncthreads();
        if (kt + 1 < nk) {
            const int buf = (kt + 1) & 1;
            const u16* a = Ab + (kt+1)*32;
            const u16* b = Bb + (kt+1)*32;
            gload16(a,         &Als[buf][tid*8]);
            gload16(a + rskip, &Als[buf][2048 + tid*8]);
            gload16(b,         &Bls[buf][tid*8]);
            gload16(b + rskip, &Bls[buf][2048 + tid*8]);
        }
        const u16* as = Als[kt & 1];
        const u16* bs = Bls[kt & 1];
        s16x8 af[4], bfr[4];
        #pragma unroll
        for (int i=0;i<4;i++) {
            af[i]  = *(const s16x8*)&as[(64*wr + 16*i + r16)*32 + swz];
            bfr[i] = *(const s16x8*)&bs[(64*wc + 16*i + r16)*32 + swz];
        }
        #pragma unroll
        for (int i=0;i<4;i++)
            #pragma unroll
            for (int j=0;j<4;j++)
                mfma_bf16(acc[i][j], af[i], bfr[j]);
    }

    float bj[4];
    #pragma unroll
    for (int j=0;j<4;j++) bj[j] = bias[n0 + 64*wc + 16*j + r16];

    if constexpr (EPI == 0 || EPI == 2) {
        u16* out = (u16*)outp;
        #pragma unroll
        for (int i=0;i<4;i++)
          #pragma unroll
          for (int r=0;r<4;r++) {
            const size_t row = m0 + 64*wr + 16*i + 4*kc + r;
            #pragma unroll
            for (int j=0;j<4;j++) {
                const int col = n0 + 64*wc + 16*j + r16;
                float v = acc[i][j][r] + bj[j];
                if constexpr (EPI == 2) v = 0.5f*v*(1.f + erff(v*0.70710678118f));
                out[row*(size_t)N + col] = f2b(v);
            }
          }
    } else if constexpr (EPI == 3) {
        float* out = (float*)outp;
        #pragma unroll
        for (int i=0;i<4;i++)
          #pragma unroll
          for (int r=0;r<4;r++) {
            const size_t row = m0 + 64*wr + 16*i + 4*kc + r;
            #pragma unroll
            for (int j=0;j<4;j++) {
                const int col = n0 + 64*wc + 16*j + r16;
                out[row*(size_t)N + col] = extra[row*(size_t)N + col] + acc[i][j][r] + bj[j];
            }
          }
    } else { // EPI == 1
        float* out = (float*)outp;
        #pragma unroll
        for (int i=0;i<4;i++)
          #pragma unroll
          for (int r=0;r<4;r++) {
            const int row = m0 + 64*wr + 16*i + 4*kc + r;
            const int win = row / 49, n = row - win*49;
            const int wpos = win & 63, b = win >> 6;
            const int n7 = n / 7;
            const int hp = (wpos >> 3)*7 + n7;
            if (hp < 4) continue;               // dropped padded rows
            const int wp = (wpos & 7)*7 + (n - n7*7);
            int h = hp + 2; if (h >= 52) h -= 52;   // (hp-4+6) % 52
            int w = wp + 6; if (w >= 56) w -= 56;
            const size_t base = (((size_t)b*52 + h)*56 + w)*384;
            #pragma unroll
            for (int j=0;j<4;j++) {
                const int col = n0 + 64*wc + 16*j + r16;
                out[base + col] = extra[base + col] + acc[i][j][r] + bj[j];
            }
          }
    }
}

// ---- MFMA attention v2 (R7-proven): builtin MFMA + scalar softmax via LDS ----
__global__ __launch_bounds__(256, 2)
void attn_mfma2(const u16* __restrict__ qkvc, const float* __restrict__ cm,
                u16* __restrict__ o, int win_base)
{
    __shared__ float Sls[4][2432];    // 9728 B per wave
    const int tid = threadIdx.x, lane = tid & 63, wv = tid >> 6;
    const int u = blockIdx.x*4 + wv;
    const int wloc = u / 12, head = u - wloc*12;
    const int wglob = win_base + wloc;
    const int wpos = wglob & 63;
    const int r16 = lane & 15, kc = lane >> 4;
    const u16* base = qkvc + (size_t)wloc*49*1152 + head*32;

    // Q,K fragments (rows padded with zeros beyond 48)
    bf16x8 qf[4], kf[4];
    #pragma unroll
    for (int i=0;i<4;i++) {
        const int row = 16*i + r16;
        s16x8 qv = {}, kv = {};
        if (row < 49) {
            const u16* p = base + (size_t)row*1152 + kc*8;
            qv = *(const s16x8*)p;
            kv = *(const s16x8*)(p + 384);
        }
        qf[i] = tob(qv); kf[i] = tob(kv);
    }

    // S = Q@K^T, scaled + mask, into LDS f32
    float* sw = Sls[wv];
    const float* cmb = cm + ((size_t)wpos*12 + head)*2401;
    #pragma unroll
    for (int i=0;i<4;i++)
      #pragma unroll
      for (int j=0;j<4;j++) {
        f32x4 s = {};
        s = __builtin_amdgcn_mfma_f32_16x16x32_bf16(qf[i], kf[j], s, 0, 0, 0);
        #pragma unroll
        for (int r=0;r<4;r++) {
            const int row = 16*i + 4*kc + r;
            const int col = 16*j + r16;
            if (row < 49 && col < 49)
                sw[row*49 + col] = s[r]*SCALE_F + cmb[row*49 + col];
        }
      }
    __syncthreads();

    // softmax: proven scalar pattern — lane r owns row r, all fp32
    float e[49]; float inv = 0.f;
    const int r = lane;
    if (r < 49) {
        #pragma unroll
        for (int c=0;c<49;c++) e[c] = sw[r*49 + c];
        float mx = -1e30f;
        #pragma unroll
        for (int c=0;c<49;c++) mx = fmaxf(mx, e[c]);
        float sm = 0.f;
        #pragma unroll
        for (int c=0;c<49;c++){ e[c] = __expf(e[c]-mx); sm += e[c]; }
        inv = 1.f/sm;
    }
    __syncthreads();   // all S reads complete before the P overlay is written

    // P (bf16, stride 72, cols 49..63 zeroed) overlays the S region
    u16* pw = (u16*)sw;
    if (r < 49) {
        #pragma unroll
        for (int w8 = 0; w8 < 8; ++w8) {
            s16x8 pk = {};
            #pragma unroll
            for (int jj=0;jj<8;jj++) {
                const int c = w8*8 + jj;
                if (c < 49) pk[jj] = (short)f2b(e[c]*inv);
            }
            *(s16x8*)&pw[r*72 + w8*8] = pk;
        }
    }
    __syncthreads();

    // V in B-fragment layout (k>48 clamped to row 0; multiplied by P==0)
    bf16x8 vf[2][2];
    const u16* vb = base + 768;
    #pragma unroll
    for (int kk=0;kk<2;kk++)
      #pragma unroll
      for (int jn=0;jn<2;jn++) {
        s16x8 vv;
        #pragma unroll
        for (int jj=0;jj<8;jj++) {
            int k = 32*kk + 8*kc + jj;
            if (k > 48) k = 0;
            vv[jj] = (short)vb[(size_t)k*1152 + 16*jn + r16];
        }
        vf[kk][jn] = tob(vv);
      }

    // O = P @ V
    f32x4 oa[4][2] = {};
    #pragma unroll
    for (int i=0;i<4;i++)
      #pragma unroll
      for (int kk=0;kk<2;kk++) {
        const bf16x8 pa = tob(*(const s16x8*)&pw[(16*i + r16)*72 + 32*kk + kc*8]);
        #pragma unroll
        for (int jn=0;jn<2;jn++)
            oa[i][jn] = __builtin_amdgcn_mfma_f32_16x16x32_bf16(pa, vf[kk][jn], oa[i][jn], 0, 0, 0);
      }

    #pragma unroll
    for (int i=0;i<4;i++)
      #pragma unroll
      for (int rr=0;rr<4;rr++) {
        const int row = 16*i + 4*kc + rr;
        if (row < 49) {
          #pragma unroll
          for (int jn=0;jn<2;jn++)
            o[(size_t)(wglob*49 + row)*384 + head*32 + 16*jn + r16] = f2b(oa[i][jn][rr]);
        }
      }
}

static int pick_chunks(size_t full, size_t avail) {
    for (int n = 1; n <= 8; n <<= 1) if (full / n <= avail) return n;
    return 8;   // R2-proven fallback (ws >= 204MB demonstrated)
}

extern "C" void kernel_launch(void* const* d_in, const int* in_sizes, int n_in,
                              void* d_out, int out_size, void* d_ws, size_t ws_size,
                              hipStream_t stream)
{
    (void)in_sizes; (void)n_in; (void)out_size;
    const float* x      = (const float*)d_in[0];
    const float* n1g    = (const float*)d_in[1];
    const float* n1b    = (const float*)d_in[2];
    const float* qkv_w  = (const float*)d_in[3];
    const float* qkv_b  = (const float*)d_in[4];
    const float* rpb    = (const float*)d_in[5];
    const float* proj_w = (const float*)d_in[6];
    const float* proj_b = (const float*)d_in[7];
    const float* n2g    = (const float*)d_in[8];
    const float* n2b    = (const float*)d_in[9];
    const float* fc1_w  = (const float*)d_in[10];
    const float* fc1_b  = (const float*)d_in[11];
    const float* fc2_w  = (const float*)d_in[12];
    const float* fc2_b  = (const float*)d_in[13];
    const float* amask  = (const float*)d_in[14];
    const float* pmask  = (const float*)d_in[15];
    const int*   ridx   = (const int*)d_in[16];

    char* ws = (char*)d_ws;
    float* cm    = (float*)(ws + OFF_CM);
    u16* wqkvT   = (u16*)(ws + OFF_WQ);
    u16* wprojT  = (u16*)(ws + OFF_WP);
    u16* wfc1T   = (u16*)(ws + OFF_W1);
    u16* wfc2T   = (u16*)(ws + OFF_W2);
    u16* awin    = (u16*)(ws + OFF_AWIN);
    u16* obuf    = (u16*)(ws + OFF_OBUF);
    u16* arena   = (u16*)(ws + OFF_ARENA);  // qkv chunk, later fc1 chunk
    u16* ln2o    = (u16*)(ws + OFF_AWIN);   // reuse (awin dead after QKV)
    float* x1    = (float*)d_out;           // x1 lives in d_out (in-place finish)

    const size_t avail = (ws_size > OFF_ARENA) ? ws_size - OFF_ARENA : 0;

    cm_kernel  <<<dim3(64,12),  256, 0, stream>>>(amask, pmask, rpb, ridx, cm);
    wconv_kernel<<<dim3(2,1152),256, 0, stream>>>(qkv_w,  wqkvT, 384, 1152);
    wconv_kernel<<<dim3(2,384), 256, 0, stream>>>(proj_w, wprojT, 384, 384);
    wconv_kernel<<<dim3(2,1536),256, 0, stream>>>(fc1_w,  wfc1T, 384, 1536);
    wconv_kernel<<<dim3(6,384), 256, 0, stream>>>(fc2_w,  wfc2T, 1536, 384);

    ln_kernel<1><<<25088, 256, 0, stream>>>(x, n1g, n1b, awin);

    // QKV + attention; chunked only if the arena is too small
    {
        const int n_attn = pick_chunks(QKV_FULL, avail);
        const int wchunk = 2048 / n_attn;          // windows per chunk
        const int rows_a = wchunk * 49;            // multiple of 128 for all n
        for (int c = 0; c < n_attn; ++c) {
            const u16* aA = awin + (size_t)c*rows_a*384;
            gemm_kernel<0><<<dim3(9, rows_a/128), 256, 0, stream>>>(
                aA, wqkvT, qkv_b, arena, nullptr, rows_a, 1152, 384);
            attn_mfma2<<<wchunk*3, 256, 0, stream>>>(arena, cm, obuf, c*wchunk);
        }
    }

    gemm_kernel<1><<<dim3(3,784), 256, 0, stream>>>(obuf, wprojT, proj_b, x1, x, 100352, 384, 384);
    ln_kernel<0><<<23296, 256, 0, stream>>>(x1, n2g, n2b, ln2o);

    // MLP; chunked only if the arena is too small
    {
        const int n_mlp = pick_chunks(FC1_FULL, avail);
        const int rows_m = 93184 / n_mlp;          // 728/n blocks, n in {1,2,4,8}
        for (int c = 0; c < n_mlp; ++c) {
            const size_t ro = (size_t)c*rows_m;
            gemm_kernel<2><<<dim3(12, rows_m/128), 256, 0, stream>>>(
                ln2o + ro*384, wfc1T, fc1_b, arena, nullptr, rows_m, 1536, 384);
            gemm_kernel<3><<<dim3(3, rows_m/128), 256, 0, stream>>>(
                arena, wfc2T, fc2_b, x1 + ro*384, x1 + ro*384, rows_m, 384, 1536);
        }
    }
}

// Round 9
// 829.133 us; speedup vs baseline: 1.7355x; 1.0059x over previous
//
#include <hip/hip_runtime.h>
#include <hip/hip_bf16.h>

typedef unsigned short u16;
typedef short s16x8 __attribute__((ext_vector_type(8)));
typedef float f32x4 __attribute__((ext_vector_type(4)));
typedef __bf16 bf16x8 __attribute__((ext_vector_type(8)));

#define SCALE_F 0.17677669529663687f

// workspace layout (bytes). Fixed part ends at 168MB (R2/R6-proven); arena adaptive.
#define OFF_CM    ((size_t)0)                 // 64*12*2401*4 = 7,375,872
#define OFF_WQ    ((size_t)8<<20)             // qkvT  1152*384*2
#define OFF_WP    (OFF_WQ + 884736)           // projT 384*384*2
#define OFF_W1    (OFF_WP + 294912)           // fc1T  1536*384*2
#define OFF_W2    (OFF_W1 + 1179648)          // fc2T  384*1536*2
#define OFF_AWIN  ((size_t)12<<20)            // 77MB: A_win -> (reuse) ln2o
#define OFF_OBUF  ((size_t)90<<20)            // 73.5MB: attention output
#define OFF_ARENA ((size_t)168<<20)           // qkv chunk / fc1 chunk (adaptive)

#define QKV_FULL  ((size_t)100352*1152*2)     // 231,211,008
#define FC1_FULL  ((size_t)93184*1536*2)      // 286,261,248

static __device__ __forceinline__ u16 f2b(float f) {
    unsigned u = __float_as_uint(f);
    u += 0x7fffu + ((u >> 16) & 1u);
    return (u16)(u >> 16);
}
static __device__ __forceinline__ float b2f(u16 u) {
    return __uint_as_float((unsigned)u << 16);
}

union frag_u { s16x8 s; bf16x8 b; };
static __device__ __forceinline__ bf16x8 tob(s16x8 v) { frag_u u; u.s = v; return u.b; }

static __device__ __forceinline__ void mfma_bf16(f32x4& d, s16x8 a, s16x8 b) {
    asm("v_mfma_f32_16x16x32_bf16 %0, %1, %2, %0" : "+v"(d) : "v"(a), "v"(b));
}

static __device__ __forceinline__ void gload16(const void* g, void* l) {
    __builtin_amdgcn_global_load_lds(
        (const __attribute__((address_space(1))) unsigned int*)g,
        (__attribute__((address_space(3))) unsigned int*)l, 16, 0, 0);
}

// ---- combined mask+bias: CM[wpos][head][r*49+c] ----
__global__ void cm_kernel(const float* __restrict__ am, const float* __restrict__ pm,
                          const float* __restrict__ rpb, const int* __restrict__ ridx,
                          float* __restrict__ cmo)
{
    const int wpos = blockIdx.x, head = blockIdx.y;
    float* o = cmo + ((size_t)wpos*12 + head)*2401;
    const float* a = am + (size_t)wpos*2401;
    const float* p = pm + (size_t)wpos*2401;
    for (int e = threadIdx.x; e < 2401; e += 256)
        o[e] = a[e] + p[e] + rpb[ridx[e]*12 + head];
}

// ---- weight transpose+convert: Wt[n][k] = bf16(W[k][n]) ----
__global__ void wconv_kernel(const float* __restrict__ w, u16* __restrict__ wt,
                             int K, int N)
{
    const int k = blockIdx.x*256 + threadIdx.x;
    const int n = blockIdx.y;
    if (k < K) wt[(size_t)n*K + k] = f2b(w[(size_t)k*N + n]);
}

// ---- layernorm; WINDOWED=1 adds roll/pad/window-partition gather ----
template<int WINDOWED>
__global__ __launch_bounds__(256, 4)
void ln_kernel(const float* __restrict__ x, const float* __restrict__ g,
               const float* __restrict__ bt, u16* __restrict__ out)
{
    const int lane = threadIdx.x & 63;
    const int row = blockIdx.x*4 + (threadIdx.x >> 6);
    u16* orow = out + (size_t)row*384;
    const float* xr;
    if (WINDOWED) {
        const int win = row / 49, n = row - win*49;
        const int wpos = win & 63, b = win >> 6;
        const int n7 = n / 7;
        const int hp = (wpos >> 3)*7 + n7;
        if (hp < 4) {                 // zero-padded rows (wave-uniform)
            #pragma unroll
            for (int j=0;j<6;j++) orow[lane + 64*j] = 0;
            return;
        }
        const int wp = (wpos & 7)*7 + (n - n7*7);
        int h = hp - 1; if (h >= 52) h -= 52;   // (hp-4+3) % 52
        int w = wp + 3; if (w >= 56) w -= 56;
        xr = x + (((size_t)b*52 + h)*56 + w)*384;
    } else {
        xr = x + (size_t)row*384;
    }
    float v[6]; float sum = 0.f;
    #pragma unroll
    for (int j=0;j<6;j++){ v[j] = xr[lane + 64*j]; sum += v[j]; }
    #pragma unroll
    for (int m=1;m<64;m<<=1) sum += __shfl_xor(sum, m);
    const float mean = sum * (1.f/384.f);
    float var = 0.f;
    #pragma unroll
    for (int j=0;j<6;j++){ float d = v[j]-mean; var += d*d; }
    #pragma unroll
    for (int m=1;m<64;m<<=1) var += __shfl_xor(var, m);
    const float rstd = rsqrtf(var*(1.f/384.f) + 1e-5f);
    #pragma unroll
    for (int j=0;j<6;j++){
        const int c = lane + 64*j;
        orow[c] = f2b((v[j]-mean)*rstd*g[c] + bt[c]);
    }
}

// ---- generic bf16 GEMM (proven body + bijective XCD swizzle): ----
// out[M][N] = A[M][K] @ Bt[N][K]^T + bias
// EPI 0: +bias -> bf16 in head-blocked qkv layout [win][sel][head][49][32]
// EPI 2: tanh-GELU(+bias) -> bf16
// EPI 1: +bias +x(shortcut) with inverse-window scatter -> f32 x1
// EPI 3: +bias +x1 -> f32 (in-place on x1)
template<int EPI>
__global__ __launch_bounds__(256, 2)
void gemm_kernel(const u16* __restrict__ A, const u16* __restrict__ Bt,
                 const float* __restrict__ bias, void* __restrict__ outp,
                 const float* __restrict__ extra, int M, int N, int K)
{
    (void)M;
    __shared__ u16 Als[2][4096];
    __shared__ u16 Bls[2][4096];
    const int tid = threadIdx.x;
    const int lane = tid & 63;
    const int wid = tid >> 6;
    const int wr = wid >> 1, wc = wid & 1;
    const int r16 = lane & 15, kc = lane >> 4;

    // bijective XCD swizzle (m204): contiguous flat-block ranges -> one XCD,
    // so the gx blocks sharing an A-panel hit the same L2.
    const int gx = gridDim.x;
    const int nwg = gx * gridDim.y;
    const int flat = blockIdx.y*gx + blockIdx.x;
    const int q8 = nwg >> 3, r8 = nwg & 7;
    const int xcd = flat & 7, idx = flat >> 3;
    const int tile = (xcd < r8 ? xcd*(q8+1) : r8*(q8+1) + (xcd-r8)*q8) + idx;
    const int ty = tile / gx;
    const int m0 = ty*128, n0 = (tile - ty*gx)*128;

    const int srow = tid >> 2, schunk = tid & 3;
    const int nk = K >> 5;

    // source-chunk XOR swizzle keeps LDS dest linear (tid*16B) but spreads banks
    const u16* Ab = A  + (size_t)(m0 + srow)*K + (schunk ^ ((srow >> 1) & 3))*8;
    const u16* Bb = Bt + (size_t)(n0 + srow)*K + (schunk ^ ((srow >> 1) & 3))*8;
    const size_t rskip = (size_t)64*K;

    gload16(Ab,         &Als[0][tid*8]);
    gload16(Ab + rskip, &Als[0][2048 + tid*8]);
    gload16(Bb,         &Bls[0][tid*8]);
    gload16(Bb + rskip, &Bls[0][2048 + tid*8]);

    f32x4 acc[4][4] = {};
    const int swz = (kc ^ ((r16 >> 1) & 3))*8;
    for (int kt = 0; kt < nk; ++kt) {
        __syncthreads();
        if (kt + 1 < nk) {
            const int buf = (kt + 1) & 1;
            const u16* a = Ab + (kt+1)*32;
            const u16* b = Bb + (kt+1)*32;
            gload16(a,         &Als[buf][tid*8]);
            gload16(a + rskip, &Als[buf][2048 + tid*8]);
            gload16(b,         &Bls[buf][tid*8]);
            gload16(b + rskip, &Bls[buf][2048 + tid*8]);
        }
        const u16* as = Als[kt & 1];
        const u16* bs = Bls[kt & 1];
        s16x8 af[4], bfr[4];
        #pragma unroll
        for (int i=0;i<4;i++) {
            af[i]  = *(const s16x8*)&as[(64*wr + 16*i + r16)*32 + swz];
            bfr[i] = *(const s16x8*)&bs[(64*wc + 16*i + r16)*32 + swz];
        }
        #pragma unroll
        for (int i=0;i<4;i++)
            #pragma unroll
            for (int j=0;j<4;j++)
                mfma_bf16(acc[i][j], af[i], bfr[j]);
    }

    float bj[4];
    #pragma unroll
    for (int j=0;j<4;j++) bj[j] = bias[n0 + 64*wc + 16*j + r16];

    if constexpr (EPI == 0) {
        // head-blocked qkv write: [win][sel(3)][head(12)][49][32]
        u16* out = (u16*)outp;
        int colbase[4];
        #pragma unroll
        for (int j=0;j<4;j++) {
            const int col = n0 + 64*wc + 16*j + r16;
            const int sel = col/384;
            const int head = (col - sel*384) >> 5;
            colbase[j] = (sel*12 + head)*1568 + (col & 31);
        }
        #pragma unroll
        for (int i=0;i<4;i++)
          #pragma unroll
          for (int r=0;r<4;r++) {
            const int row = m0 + 64*wr + 16*i + 4*kc + r;
            const int win = row/49, r49 = row - win*49;
            u16* dst = out + (size_t)win*56448 + (size_t)r49*32;
            #pragma unroll
            for (int j=0;j<4;j++)
                dst[colbase[j]] = f2b(acc[i][j][r] + bj[j]);
          }
    } else if constexpr (EPI == 2) {
        u16* out = (u16*)outp;
        #pragma unroll
        for (int i=0;i<4;i++)
          #pragma unroll
          for (int r=0;r<4;r++) {
            const size_t row = m0 + 64*wr + 16*i + 4*kc + r;
            #pragma unroll
            for (int j=0;j<4;j++) {
                const int col = n0 + 64*wc + 16*j + r16;
                float v = acc[i][j][r] + bj[j];
                // tanh-form GELU: v*sigmoid(2u), u = v(c0 + c1*v^2)
                const float u2 = v*(0.79788456f + 0.035677408f*v*v);
                v = v / (1.f + __expf(-2.f*u2));
                out[row*(size_t)N + col] = f2b(v);
            }
          }
    } else if constexpr (EPI == 3) {
        float* out = (float*)outp;
        #pragma unroll
        for (int i=0;i<4;i++)
          #pragma unroll
          for (int r=0;r<4;r++) {
            const size_t row = m0 + 64*wr + 16*i + 4*kc + r;
            #pragma unroll
            for (int j=0;j<4;j++) {
                const int col = n0 + 64*wc + 16*j + r16;
                out[row*(size_t)N + col] = extra[row*(size_t)N + col] + acc[i][j][r] + bj[j];
            }
          }
    } else { // EPI == 1
        float* out = (float*)outp;
        #pragma unroll
        for (int i=0;i<4;i++)
          #pragma unroll
          for (int r=0;r<4;r++) {
            const int row = m0 + 64*wr + 16*i + 4*kc + r;
            const int win = row / 49, n = row - win*49;
            const int wpos = win & 63, b = win >> 6;
            const int n7 = n / 7;
            const int hp = (wpos >> 3)*7 + n7;
            if (hp < 4) continue;               // dropped padded rows
            const int wp = (wpos & 7)*7 + (n - n7*7);
            int h = hp + 2; if (h >= 52) h -= 52;   // (hp-4+6) % 52
            int w = wp + 6; if (w >= 56) w -= 56;
            const size_t base = (((size_t)b*52 + h)*56 + w)*384;
            #pragma unroll
            for (int j=0;j<4;j++) {
                const int col = n0 + 64*wc + 16*j + r16;
                out[base + col] = extra[base + col] + acc[i][j][r] + bj[j];
            }
          }
    }
}

// ---- MFMA attention v2 (R7-proven math) on head-blocked qkv layout ----
// qkv arena: [win][sel(3)][head(12)][49][32] bf16 — rows are 64B, dense.
__global__ __launch_bounds__(256, 2)
void attn_mfma2(const u16* __restrict__ qkvc, const float* __restrict__ cm,
                u16* __restrict__ o, int win_base)
{
    __shared__ float Sls[4][2432];    // 9728 B per wave
    const int tid = threadIdx.x, lane = tid & 63, wv = tid >> 6;
    const int u = blockIdx.x*4 + wv;
    const int wloc = u / 12, head = u - wloc*12;
    const int wglob = win_base + wloc;
    const int wpos = wglob & 63;
    const int r16 = lane & 15, kc = lane >> 4;
    const u16* bq = qkvc + ((size_t)(wloc*3 + 0)*12 + head)*1568;
    const u16* bk = qkvc + ((size_t)(wloc*3 + 1)*12 + head)*1568;
    const u16* bv = qkvc + ((size_t)(wloc*3 + 2)*12 + head)*1568;

    // Q,K fragments (rows padded with zeros beyond 48)
    bf16x8 qf[4], kf[4];
    #pragma unroll
    for (int i=0;i<4;i++) {
        const int row = 16*i + r16;
        s16x8 qv = {}, kv = {};
        if (row < 49) {
            qv = *(const s16x8*)&bq[row*32 + kc*8];
            kv = *(const s16x8*)&bk[row*32 + kc*8];
        }
        qf[i] = tob(qv); kf[i] = tob(kv);
    }

    // S = Q@K^T, scaled + mask, into LDS f32
    float* sw = Sls[wv];
    const float* cmb = cm + ((size_t)wpos*12 + head)*2401;
    #pragma unroll
    for (int i=0;i<4;i++)
      #pragma unroll
      for (int j=0;j<4;j++) {
        f32x4 s = {};
        s = __builtin_amdgcn_mfma_f32_16x16x32_bf16(qf[i], kf[j], s, 0, 0, 0);
        #pragma unroll
        for (int r=0;r<4;r++) {
            const int row = 16*i + 4*kc + r;
            const int col = 16*j + r16;
            if (row < 49 && col < 49)
                sw[row*49 + col] = s[r]*SCALE_F + cmb[row*49 + col];
        }
      }
    __syncthreads();

    // softmax: proven scalar pattern — lane r owns row r, all fp32
    float e[49]; float inv = 0.f;
    const int r = lane;
    if (r < 49) {
        #pragma unroll
        for (int c=0;c<49;c++) e[c] = sw[r*49 + c];
        float mx = -1e30f;
        #pragma unroll
        for (int c=0;c<49;c++) mx = fmaxf(mx, e[c]);
        float sm = 0.f;
        #pragma unroll
        for (int c=0;c<49;c++){ e[c] = __expf(e[c]-mx); sm += e[c]; }
        inv = 1.f/sm;
    }
    __syncthreads();   // all S reads complete before the P overlay is written

    // P (bf16, stride 72, cols 49..63 zeroed) overlays the S region
    u16* pw = (u16*)sw;
    if (r < 49) {
        #pragma unroll
        for (int w8 = 0; w8 < 8; ++w8) {
            s16x8 pk = {};
            #pragma unroll
            for (int jj=0;jj<8;jj++) {
                const int c = w8*8 + jj;
                if (c < 49) pk[jj] = (short)f2b(e[c]*inv);
            }
            *(s16x8*)&pw[r*72 + w8*8] = pk;
        }
    }
    __syncthreads();

    // V in B-fragment layout (k>48 clamped to row 0; multiplied by P==0)
    bf16x8 vf[2][2];
    #pragma unroll
    for (int kk=0;kk<2;kk++)
      #pragma unroll
      for (int jn=0;jn<2;jn++) {
        s16x8 vv;
        #pragma unroll
        for (int jj=0;jj<8;jj++) {
            int k = 32*kk + 8*kc + jj;
            if (k > 48) k = 0;
            vv[jj] = (short)bv[k*32 + 16*jn + r16];
        }
        vf[kk][jn] = tob(vv);
      }

    // O = P @ V
    f32x4 oa[4][2] = {};
    #pragma unroll
    for (int i=0;i<4;i++)
      #pragma unroll
      for (int kk=0;kk<2;kk++) {
        const bf16x8 pa = tob(*(const s16x8*)&pw[(16*i + r16)*72 + 32*kk + kc*8]);
        #pragma unroll
        for (int jn=0;jn<2;jn++)
            oa[i][jn] = __builtin_amdgcn_mfma_f32_16x16x32_bf16(pa, vf[kk][jn], oa[i][jn], 0, 0, 0);
      }

    #pragma unroll
    for (int i=0;i<4;i++)
      #pragma unroll
      for (int rr=0;rr<4;rr++) {
        const int row = 16*i + 4*kc + rr;
        if (row < 49) {
          #pragma unroll
          for (int jn=0;jn<2;jn++)
            o[(size_t)(wglob*49 + row)*384 + head*32 + 16*jn + r16] = f2b(oa[i][jn][rr]);
        }
      }
}

static int pick_chunks(size_t full, size_t avail) {
    for (int n = 1; n <= 8; n <<= 1) if (full / n <= avail) return n;
    return 8;   // R2-proven fallback (ws >= 204MB demonstrated)
}

extern "C" void kernel_launch(void* const* d_in, const int* in_sizes, int n_in,
                              void* d_out, int out_size, void* d_ws, size_t ws_size,
                              hipStream_t stream)
{
    (void)in_sizes; (void)n_in; (void)out_size;
    const float* x      = (const float*)d_in[0];
    const float* n1g    = (const float*)d_in[1];
    const float* n1b    = (const float*)d_in[2];
    const float* qkv_w  = (const float*)d_in[3];
    const float* qkv_b  = (const float*)d_in[4];
    const float* rpb    = (const float*)d_in[5];
    const float* proj_w = (const float*)d_in[6];
    const float* proj_b = (const float*)d_in[7];
    const float* n2g    = (const float*)d_in[8];
    const float* n2b    = (const float*)d_in[9];
    const float* fc1_w  = (const float*)d_in[10];
    const float* fc1_b  = (const float*)d_in[11];
    const float* fc2_w  = (const float*)d_in[12];
    const float* fc2_b  = (const float*)d_in[13];
    const float* amask  = (const float*)d_in[14];
    const float* pmask  = (const float*)d_in[15];
    const int*   ridx   = (const int*)d_in[16];

    char* ws = (char*)d_ws;
    float* cm    = (float*)(ws + OFF_CM);
    u16* wqkvT   = (u16*)(ws + OFF_WQ);
    u16* wprojT  = (u16*)(ws + OFF_WP);
    u16* wfc1T   = (u16*)(ws + OFF_W1);
    u16* wfc2T   = (u16*)(ws + OFF_W2);
    u16* awin    = (u16*)(ws + OFF_AWIN);
    u16* obuf    = (u16*)(ws + OFF_OBUF);
    u16* arena   = (u16*)(ws + OFF_ARENA);  // qkv chunk, later fc1 chunk
    u16* ln2o    = (u16*)(ws + OFF_AWIN);   // reuse (awin dead after QKV)
    float* x1    = (float*)d_out;           // x1 lives in d_out (in-place finish)

    const size_t avail = (ws_size > OFF_ARENA) ? ws_size - OFF_ARENA : 0;

    cm_kernel  <<<dim3(64,12),  256, 0, stream>>>(amask, pmask, rpb, ridx, cm);
    wconv_kernel<<<dim3(2,1152),256, 0, stream>>>(qkv_w,  wqkvT, 384, 1152);
    wconv_kernel<<<dim3(2,384), 256, 0, stream>>>(proj_w, wprojT, 384, 384);
    wconv_kernel<<<dim3(2,1536),256, 0, stream>>>(fc1_w,  wfc1T, 384, 1536);
    wconv_kernel<<<dim3(6,384), 256, 0, stream>>>(fc2_w,  wfc2T, 1536, 384);

    ln_kernel<1><<<25088, 256, 0, stream>>>(x, n1g, n1b, awin);

    // QKV + attention; chunked only if the arena is too small
    {
        const int n_attn = pick_chunks(QKV_FULL, avail);
        const int wchunk = 2048 / n_attn;          // windows per chunk
        const int rows_a = wchunk * 49;            // multiple of 128 for all n
        for (int c = 0; c < n_attn; ++c) {
            const u16* aA = awin + (size_t)c*rows_a*384;
            gemm_kernel<0><<<dim3(9, rows_a/128), 256, 0, stream>>>(
                aA, wqkvT, qkv_b, arena, nullptr, rows_a, 1152, 384);
            attn_mfma2<<<wchunk*3, 256, 0, stream>>>(arena, cm, obuf, c*wchunk);
        }
    }

    gemm_kernel<1><<<dim3(3,784), 256, 0, stream>>>(obuf, wprojT, proj_b, x1, x, 100352, 384, 384);
    ln_kernel<0><<<23296, 256, 0, stream>>>(x1, n2g, n2b, ln2o);

    // MLP; chunked only if the arena is too small
    {
        const int n_mlp = pick_chunks(FC1_FULL, avail);
        const int rows_m = 93184 / n_mlp;          // 728/n blocks, n in {1,2,4,8}
        for (int c = 0; c < n_mlp; ++c) {
            const size_t ro = (size_t)c*rows_m;
            gemm_kernel<2><<<dim3(12, rows_m/128), 256, 0, stream>>>(
                ln2o + ro*384, wfc1T, fc1_b, arena, nullptr, rows_m, 1536, 384);
            gemm_kernel<3><<<dim3(3, rows_m/128), 256, 0, stream>>>(
                arena, wfc2T, fc2_b, x1 + ro*384, x1 + ro*384, rows_m, 384, 1536);
        }
    }
}